// Round 9
// baseline (129.270 us; speedup 1.0000x reference)
//
#include <hip/hip_runtime.h>

#define DIM  128
#define HID  32
#define KTOT 384          // 3*DIM
#define TPW  16           // edges per wave-tile

typedef __attribute__((ext_vector_type(4))) float f32x4;
typedef __attribute__((ext_vector_type(8))) int   i32x8;

// ---- fp4 e2m1 helpers -----------------------------------------------------
// encode f32 -> e2m1 nibble (prep side only)
static __device__ __forceinline__ unsigned enc_fp4(float x) {
    unsigned s = (x < 0.f) ? 8u : 0u;
    float a = fabsf(x);
    unsigned m = (a >= 0.25f) + (a >= 0.75f) + (a >= 1.25f) + (a >= 1.75f)
               + (a >= 2.5f)  + (a >= 3.5f)  + (a >= 5.0f);
    return s | m;
}

// ---------------------------------------------------------------------------
// R16: branch-free SWAR fp4xfp4 -> fp8(e4m3) elementwise product.
// Replaces the dec_fp4 scalar fallback (~400 VALU/tile, the likely cause of
// R13's VALUBusy=41%). Identity (verified over all cases):
//   mag lut: t -> e4m3 {0x00->0x38(zerofix),0x30,0x38,0x3C,0x40,0x44,0x48,0x4C}
//   product byte = magA + magB - 0x38 + (magA & magB & 0x04)>>2,  then
//   zero-mask (nz lut) and OR sign ((nibA^nibB)&8)<<4.
// Packed-byte safe: per-byte sums in [0x60,0x98] (no carry), -0x38 no borrow
// after zero-fix, +mm<=1 no carry. Bit-exact vs f32 path (all e2m1 products
// are exactly representable in e4m3) -> absmax must stay 2.578125.
// ~156 VALU/tile vs ~400.
// ---------------------------------------------------------------------------
static __device__ __forceinline__ i32x8 prod_fp4_to_fp8(int4 a, int4 b) {
    const unsigned MAGZ = 0x3C383038u;  // t=0..3: {zero->0x38, 0x30, 0x38, 0x3C}
    const unsigned MAGH = 0x4C484440u;  // t=4..7: {0x40, 0x44, 0x48, 0x4C}
    const unsigned NZL  = 0xFFFFFF00u;  // t=0 -> 0x00 else 0xFF
    const unsigned NZH  = 0xFFFFFFFFu;
    const unsigned* aw = (const unsigned*)&a;
    const unsigned* bw = (const unsigned*)&b;
    i32x8 r;
#pragma unroll
    for (int i = 0; i < 4; i++) {
        unsigned xa = aw[i], xb = bw[i], xs = xa ^ xb;
        // even elements (low nibbles of each byte)
        unsigned tae = xa & 0x07070707u, tbe = xb & 0x07070707u;
        unsigned mae = __builtin_amdgcn_perm(MAGH, MAGZ, tae);
        unsigned nae = __builtin_amdgcn_perm(NZH,  NZL,  tae);
        unsigned mbe = __builtin_amdgcn_perm(MAGH, MAGZ, tbe);
        unsigned nbe = __builtin_amdgcn_perm(NZH,  NZL,  tbe);
        unsigned pe  = mae + mbe - 0x38383838u;
        pe += (mae & mbe & 0x04040404u) >> 2;
        pe &= nae & nbe;
        pe |= (xs & 0x08080808u) << 4;
        // odd elements (high nibbles)
        unsigned xao = xa >> 4, xbo = xb >> 4;
        unsigned tao = xao & 0x07070707u, tbo = xbo & 0x07070707u;
        unsigned mao = __builtin_amdgcn_perm(MAGH, MAGZ, tao);
        unsigned nao = __builtin_amdgcn_perm(NZH,  NZL,  tao);
        unsigned mbo = __builtin_amdgcn_perm(MAGH, MAGZ, tbo);
        unsigned nbo = __builtin_amdgcn_perm(NZH,  NZL,  tbo);
        unsigned po  = mao + mbo - 0x38383838u;
        po += (mao & mbo & 0x04040404u) >> 2;
        po &= nao & nbo;
        po |= ((xs >> 4) & 0x08080808u) << 4;
        // interleave to element order: (e0,e1,e2,e3), (e4,e5,e6,e7)
        // perm(s0,s1,sel): sel 0-3 -> s1 bytes, 4-7 -> s0 bytes
        r[2*i]   = (int)__builtin_amdgcn_perm(pe, po, 0x01050004u);
        r[2*i+1] = (int)__builtin_amdgcn_perm(pe, po, 0x03070206u);
    }
    return r;
}

static __device__ __forceinline__ i32x8 ld32(const unsigned char* p) {
    int4 lo = *(const int4*)p;
    int4 hi = *(const int4*)(p + 16);
    i32x8 v;
    v[0] = lo.x; v[1] = lo.y; v[2] = lo.z; v[3] = lo.w;
    v[4] = hi.x; v[5] = hi.y; v[6] = hi.z; v[7] = hi.w;
    return v;
}

static __device__ __forceinline__ i32x8 lo4(int4 v) {
    i32x8 r;
    r[0] = v.x; r[1] = v.y; r[2] = v.z; r[3] = v.w;
    r[4] = 0; r[5] = 0; r[6] = 0; r[7] = 0;
    return r;
}

// FMT codes: 0=fp8(e4m3), 4=fp4(e2m1). unit e8m0 scales (0x7F per byte).
#define MFMA_F4(A, B, C) __builtin_amdgcn_mfma_scale_f32_16x16x128_f8f6f4( \
                             (A), (B), (C), 4, 4, 0, 0x7F7F7F7F, 0, 0x7F7F7F7F)
#define MFMA_F8(A, B, C) __builtin_amdgcn_mfma_scale_f32_16x16x128_f8f6f4( \
                             (A), (B), (C), 0, 0, 0, 0x7F7F7F7F, 0, 0x7F7F7F7F)

// ---------------------------------------------------------------------------
// Kernel 0: wsum[r] = sum_d W[r][d]
// ---------------------------------------------------------------------------
__global__ __launch_bounds__(256) void wsum_kernel(const float* __restrict__ W,
                                                   float* __restrict__ wsum)
{
    const int wv = threadIdx.x >> 6, lane = threadIdx.x & 63;
    const int r = blockIdx.x * 4 + wv;            // 0..127
    float2 v = *(const float2*)(W + (size_t)r * DIM + lane * 2);
    float s = v.x + v.y;
    s += __shfl_xor(s, 1);  s += __shfl_xor(s, 2);  s += __shfl_xor(s, 4);
    s += __shfl_xor(s, 8);  s += __shfl_xor(s, 16); s += __shfl_xor(s, 32);
    if (lane == 0) wsum[r] = s;
}

// ---------------------------------------------------------------------------
// Kernel 1 prep (unchanged from R12/fp4 version)
// ---------------------------------------------------------------------------
__global__ __launch_bounds__(256) void prep_kernel(
    const float* __restrict__ z, const float* __restrict__ w1,
    const float* __restrict__ wsum,
    unsigned char* __restrict__ zb4, unsigned char* __restrict__ w1T8,
    unsigned char* __restrict__ w1T4,
    float* __restrict__ s1, float* __restrict__ s2,
    int nNodes, int nNodeBlk)
{
    const int b = blockIdx.x;
    const int tid = threadIdx.x;
    if (b < nNodeBlk) {
        const int n = b * 8 + (tid >> 5);
        const int l32 = tid & 31;
        if (n >= nNodes) return;                   // half-wave-uniform exit

        float4 v = *(const float4*)(z + (size_t)n * DIM + l32 * 4);
        float4 w = *(const float4*)(wsum + l32 * 4);

        float a1 = v.x * w.x + v.y * w.y + v.z * w.z + v.w * w.w;
        float a2 = v.x + v.y + v.z + v.w;

        unsigned b0 = enc_fp4(v.x) | (enc_fp4(v.y) << 4);
        unsigned b1 = enc_fp4(v.z) | (enc_fp4(v.w) << 4);
        *(unsigned short*)(zb4 + (size_t)n * 64 + l32 * 2) =
            (unsigned short)(b0 | (b1 << 8));

        a1 += __shfl_xor(a1, 1);  a1 += __shfl_xor(a1, 2);  a1 += __shfl_xor(a1, 4);
        a1 += __shfl_xor(a1, 8);  a1 += __shfl_xor(a1, 16);
        a2 += __shfl_xor(a2, 1);  a2 += __shfl_xor(a2, 2);  a2 += __shfl_xor(a2, 4);
        a2 += __shfl_xor(a2, 8);  a2 += __shfl_xor(a2, 16);
        if (l32 == 0) { s1[n] = a1; s2[n] = a2; }
    } else if (b < nNodeBlk + 48) {
        const int idx = (b - nNodeBlk) * 256 + tid;    // 0..12287 exact
        const int k = idx >> 5, h = idx & 31;
        unsigned r = __builtin_amdgcn_cvt_pk_fp8_f32(w1[idx], 0.f, 0u, false);
        w1T8[(size_t)h * KTOT + k] = (unsigned char)(r & 0xff);
    } else {
        const int idx2 = (b - nNodeBlk - 48) * 256 + tid;  // 0..6143 exact
        const int k2 = idx2 >> 5, h = idx2 & 31;           // k2: byte (2 k's)
        float va = w1[(2 * k2) * 32 + h];
        float vb = w1[(2 * k2 + 1) * 32 + h];
        w1T4[(size_t)h * (KTOT / 2) + k2] =
            (unsigned char)(enc_fp4(va) | (enc_fp4(vb) << 4));
    }
}

// ---------------------------------------------------------------------------
// Kernel 2: edge kernel — R12 fp4 structure + R16 SWAR product.
// launch_bounds(256,2): natural 44 VGPR (R14 lesson: don't squeeze below
// the working set — forced 32 VGPR spilled, WRITE_SIZE 3.9->34.8 MB).
// grid 2048 (R15: occupancy-neutral but harmless; keeps headroom if the
// VALU cut shifts the balance).
// ---------------------------------------------------------------------------
__global__ __launch_bounds__(256, 2) void edge_kernel(
    const unsigned char* __restrict__ zb4, const int* __restrict__ ei,
    const float* __restrict__ s1, const float* __restrict__ s2,
    const unsigned char* __restrict__ w1T8, const unsigned char* __restrict__ w1T4,
    const float* __restrict__ b1,
    const float* __restrict__ w2, const float* __restrict__ b2,
    const float* __restrict__ bias, float* __restrict__ out,
    int nE, int nTiles)
{
    const int lane = threadIdx.x & 63;
    const int wv   = threadIdx.x >> 6;
    const int l15  = lane & 15;
    const int quad = lane >> 4;

    const int t0 = blockIdx.x * 4 + wv;
    const int nW = gridDim.x * 4;
    if (t0 >= nTiles) return;

    i32x8 B0c0, B0c1, B1c0, B1c1, B0c2, B1c2;
    {
        const unsigned char* p0 = w1T4 + (size_t)l15 * (KTOT / 2) + quad * 16;
        const unsigned char* p1 = w1T4 + (size_t)(16 + l15) * (KTOT / 2) + quad * 16;
        B0c0 = lo4(*(const int4*)(p0));
        B0c1 = lo4(*(const int4*)(p0 + 64));
        B1c0 = lo4(*(const int4*)(p1));
        B1c1 = lo4(*(const int4*)(p1 + 64));
        B0c2 = ld32(w1T8 + (size_t)l15 * KTOT + 256 + quad * 32);
        B1c2 = ld32(w1T8 + (size_t)(16 + l15) * KTOT + 256 + quad * 32);
    }
    const float b1a = b1[l15],      w2a = w2[l15];
    const float b1b = b1[16 + l15], w2b = w2[16 + l15];
    const float cbias = bias[0] + b2[0];

    for (int t = t0; t < nTiles; t += nW) {
        const int e = t * TPW + l15;
        int s_ = 0, d_ = 0;
        if (e < nE) { s_ = ei[e]; d_ = ei[nE + e]; }
        const float bil = s1[s_] * s2[d_];     // f32 path, lane l15 = edge l15

        // fp4 row gathers: ONE dwordx4 per row (16 B at quad*16)
        int4 zs4 = *(const int4*)(zb4 + (size_t)s_ * 64 + quad * 16);
        int4 zd4 = *(const int4*)(zb4 + (size_t)d_ * 64 + quad * 16);

        f32x4 acc0 = {0.f, 0.f, 0.f, 0.f};
        f32x4 acc1 = {0.f, 0.f, 0.f, 0.f};
        i32x8 zsA = lo4(zs4), zdA = lo4(zd4);
        acc0 = MFMA_F4(zsA, B0c0, acc0);
        acc1 = MFMA_F4(zsA, B1c0, acc1);
        acc0 = MFMA_F4(zdA, B0c1, acc0);
        acc1 = MFMA_F4(zdA, B1c1, acc1);
        i32x8 p8 = prod_fp4_to_fp8(zs4, zd4);
        acc0 = MFMA_F8(p8, B0c2, acc0);
        acc1 = MFMA_F8(p8, B1c2, acc1);

        // epilogue (validated R3..R8): C/D col=l15 (h), row=quad*4+r (edge)
        const int e0 = t * TPW;
#pragma unroll
        for (int r = 0; r < 4; r++) {
            float v = fmaxf(acc0[r] + b1a, 0.f) * w2a
                    + fmaxf(acc1[r] + b1b, 0.f) * w2b;
            v += __shfl_xor(v, 1); v += __shfl_xor(v, 2);
            v += __shfl_xor(v, 4); v += __shfl_xor(v, 8);
            const int eL = quad * 4 + r;
            const float bilr = __shfl(bil, eL);
            if (l15 == r && (e0 + eL) < nE)
                out[e0 + eL] = v + bilr + cbias;
        }
    }
}

// ---------------------------------------------------------------------------
// Workspace: zb4 uchar[nNodes*64] | s1 f32[nNodes] | s2 f32[nNodes]
//          | wsum f32[128] | w1T8 uchar[32*384] | w1T4 uchar[32*192] (~7.2 MB)
// ---------------------------------------------------------------------------
extern "C" void kernel_launch(void* const* d_in, const int* in_sizes, int n_in,
                              void* d_out, int out_size, void* d_ws, size_t ws_size,
                              hipStream_t stream)
{
    const float* z    = (const float*)d_in[0];
    const int*   ei   = (const int*)d_in[1];
    const float* W    = (const float*)d_in[2];
    const float* bias = (const float*)d_in[3];
    const float* w1   = (const float*)d_in[4];
    const float* b1   = (const float*)d_in[5];
    const float* w2   = (const float*)d_in[6];
    const float* b2   = (const float*)d_in[7];
    float* out = (float*)d_out;

    const int nNodes = in_sizes[0] / DIM;
    const int nE = out_size;

    unsigned char* zb4 = (unsigned char*)d_ws;
    float* s1   = (float*)(zb4 + (size_t)nNodes * 64);
    float* s2   = s1 + nNodes;
    float* wsum = s2 + nNodes;
    unsigned char* w1T8 = (unsigned char*)(wsum + DIM);
    unsigned char* w1T4 = w1T8 + (size_t)HID * KTOT;

    wsum_kernel<<<32, 256, 0, stream>>>(W, wsum);

    const int nNodeBlk = (nNodes + 7) / 8;
    prep_kernel<<<nNodeBlk + 48 + 24, 256, 0, stream>>>(z, w1, wsum, zb4, w1T8,
                                                        w1T4, s1, s2,
                                                        nNodes, nNodeBlk);

    const int nTiles = (nE + TPW - 1) / TPW;
    int grid = 2048;
    if (grid * 4 > nTiles) grid = (nTiles + 3) / 4;
    edge_kernel<<<grid, 256, 0, stream>>>(zb4, ei, s1, s2, w1T8, w1T4,
                                          b1, w2, b2, bias, out, nE, nTiles);
}

// Round 10
// 125.921 us; speedup vs baseline: 1.0266x; 1.0266x over previous
//
#include <hip/hip_runtime.h>

#define DIM  128
#define HID  32
#define KTOT 384          // 3*DIM
#define TPW  16           // edges per wave-tile

typedef __attribute__((ext_vector_type(4))) float f32x4;
typedef __attribute__((ext_vector_type(8))) int   i32x8;

// ---- fp4 e2m1 helpers -----------------------------------------------------
// encode f32 -> e2m1 nibble (prep side only)
static __device__ __forceinline__ unsigned enc_fp4(float x) {
    unsigned s = (x < 0.f) ? 8u : 0u;
    float a = fabsf(x);
    unsigned m = (a >= 0.25f) + (a >= 0.75f) + (a >= 1.25f) + (a >= 1.75f)
               + (a >= 2.5f)  + (a >= 3.5f)  + (a >= 5.0f);
    return s | m;
}

// ---------------------------------------------------------------------------
// R16 SWAR fp4xfp4 -> fp8(e4m3) elementwise product (bit-exact, validated:
// absmax unchanged at 2.578125 in R16 bench).
// ---------------------------------------------------------------------------
static __device__ __forceinline__ i32x8 prod_fp4_to_fp8(int4 a, int4 b) {
    const unsigned MAGZ = 0x3C383038u;  // t=0..3: {zero->0x38, 0x30, 0x38, 0x3C}
    const unsigned MAGH = 0x4C484440u;  // t=4..7: {0x40, 0x44, 0x48, 0x4C}
    const unsigned NZL  = 0xFFFFFF00u;  // t=0 -> 0x00 else 0xFF
    const unsigned NZH  = 0xFFFFFFFFu;
    const unsigned* aw = (const unsigned*)&a;
    const unsigned* bw = (const unsigned*)&b;
    i32x8 r;
#pragma unroll
    for (int i = 0; i < 4; i++) {
        unsigned xa = aw[i], xb = bw[i], xs = xa ^ xb;
        unsigned tae = xa & 0x07070707u, tbe = xb & 0x07070707u;
        unsigned mae = __builtin_amdgcn_perm(MAGH, MAGZ, tae);
        unsigned nae = __builtin_amdgcn_perm(NZH,  NZL,  tae);
        unsigned mbe = __builtin_amdgcn_perm(MAGH, MAGZ, tbe);
        unsigned nbe = __builtin_amdgcn_perm(NZH,  NZL,  tbe);
        unsigned pe  = mae + mbe - 0x38383838u;
        pe += (mae & mbe & 0x04040404u) >> 2;
        pe &= nae & nbe;
        pe |= (xs & 0x08080808u) << 4;
        unsigned xao = xa >> 4, xbo = xb >> 4;
        unsigned tao = xao & 0x07070707u, tbo = xbo & 0x07070707u;
        unsigned mao = __builtin_amdgcn_perm(MAGH, MAGZ, tao);
        unsigned nao = __builtin_amdgcn_perm(NZH,  NZL,  tao);
        unsigned mbo = __builtin_amdgcn_perm(MAGH, MAGZ, tbo);
        unsigned nbo = __builtin_amdgcn_perm(NZH,  NZL,  tbo);
        unsigned po  = mao + mbo - 0x38383838u;
        po += (mao & mbo & 0x04040404u) >> 2;
        po &= nao & nbo;
        po |= ((xs >> 4) & 0x08080808u) << 4;
        r[2*i]   = (int)__builtin_amdgcn_perm(pe, po, 0x01050004u);
        r[2*i+1] = (int)__builtin_amdgcn_perm(pe, po, 0x03070206u);
    }
    return r;
}

static __device__ __forceinline__ i32x8 ld32(const unsigned char* p) {
    int4 lo = *(const int4*)p;
    int4 hi = *(const int4*)(p + 16);
    i32x8 v;
    v[0] = lo.x; v[1] = lo.y; v[2] = lo.z; v[3] = lo.w;
    v[4] = hi.x; v[5] = hi.y; v[6] = hi.z; v[7] = hi.w;
    return v;
}

static __device__ __forceinline__ i32x8 lo4(int4 v) {
    i32x8 r;
    r[0] = v.x; r[1] = v.y; r[2] = v.z; r[3] = v.w;
    r[4] = 0; r[5] = 0; r[6] = 0; r[7] = 0;
    return r;
}

// FMT codes: 0=fp8(e4m3), 4=fp4(e2m1). unit e8m0 scales (0x7F per byte).
#define MFMA_F4(A, B, C) __builtin_amdgcn_mfma_scale_f32_16x16x128_f8f6f4( \
                             (A), (B), (C), 4, 4, 0, 0x7F7F7F7F, 0, 0x7F7F7F7F)
#define MFMA_F8(A, B, C) __builtin_amdgcn_mfma_scale_f32_16x16x128_f8f6f4( \
                             (A), (B), (C), 0, 0, 0, 0x7F7F7F7F, 0, 0x7F7F7F7F)

// ---------------------------------------------------------------------------
// Kernel 0: wsum[r] = sum_d W[r][d]
// ---------------------------------------------------------------------------
__global__ __launch_bounds__(256) void wsum_kernel(const float* __restrict__ W,
                                                   float* __restrict__ wsum)
{
    const int wv = threadIdx.x >> 6, lane = threadIdx.x & 63;
    const int r = blockIdx.x * 4 + wv;            // 0..127
    float2 v = *(const float2*)(W + (size_t)r * DIM + lane * 2);
    float s = v.x + v.y;
    s += __shfl_xor(s, 1);  s += __shfl_xor(s, 2);  s += __shfl_xor(s, 4);
    s += __shfl_xor(s, 8);  s += __shfl_xor(s, 16); s += __shfl_xor(s, 32);
    if (lane == 0) wsum[r] = s;
}

// ---------------------------------------------------------------------------
// Kernel 1 prep (unchanged from R12/fp4 version)
// ---------------------------------------------------------------------------
__global__ __launch_bounds__(256) void prep_kernel(
    const float* __restrict__ z, const float* __restrict__ w1,
    const float* __restrict__ wsum,
    unsigned char* __restrict__ zb4, unsigned char* __restrict__ w1T8,
    unsigned char* __restrict__ w1T4,
    float* __restrict__ s1, float* __restrict__ s2,
    int nNodes, int nNodeBlk)
{
    const int b = blockIdx.x;
    const int tid = threadIdx.x;
    if (b < nNodeBlk) {
        const int n = b * 8 + (tid >> 5);
        const int l32 = tid & 31;
        if (n >= nNodes) return;                   // half-wave-uniform exit

        float4 v = *(const float4*)(z + (size_t)n * DIM + l32 * 4);
        float4 w = *(const float4*)(wsum + l32 * 4);

        float a1 = v.x * w.x + v.y * w.y + v.z * w.z + v.w * w.w;
        float a2 = v.x + v.y + v.z + v.w;

        unsigned b0 = enc_fp4(v.x) | (enc_fp4(v.y) << 4);
        unsigned b1 = enc_fp4(v.z) | (enc_fp4(v.w) << 4);
        *(unsigned short*)(zb4 + (size_t)n * 64 + l32 * 2) =
            (unsigned short)(b0 | (b1 << 8));

        a1 += __shfl_xor(a1, 1);  a1 += __shfl_xor(a1, 2);  a1 += __shfl_xor(a1, 4);
        a1 += __shfl_xor(a1, 8);  a1 += __shfl_xor(a1, 16);
        a2 += __shfl_xor(a2, 1);  a2 += __shfl_xor(a2, 2);  a2 += __shfl_xor(a2, 4);
        a2 += __shfl_xor(a2, 8);  a2 += __shfl_xor(a2, 16);
        if (l32 == 0) { s1[n] = a1; s2[n] = a2; }
    } else if (b < nNodeBlk + 48) {
        const int idx = (b - nNodeBlk) * 256 + tid;    // 0..12287 exact
        const int k = idx >> 5, h = idx & 31;
        unsigned r = __builtin_amdgcn_cvt_pk_fp8_f32(w1[idx], 0.f, 0u, false);
        w1T8[(size_t)h * KTOT + k] = (unsigned char)(r & 0xff);
    } else {
        const int idx2 = (b - nNodeBlk - 48) * 256 + tid;  // 0..6143 exact
        const int k2 = idx2 >> 5, h = idx2 & 31;           // k2: byte (2 k's)
        float va = w1[(2 * k2) * 32 + h];
        float vb = w1[(2 * k2 + 1) * 32 + h];
        w1T4[(size_t)h * (KTOT / 2) + k2] =
            (unsigned char)(enc_fp4(va) | (enc_fp4(vb) << 4));
    }
}

// ---------------------------------------------------------------------------
// Kernel 2: edge kernel — R17: OPERAND-SWAPPED MFMA epilogue.
// A=weights (l15 = h-row "m"), B=z-rows (l15 = edge-col "n"): same products,
// same k-order -> bit-identical result; C/D layout flips to col=edge (l15),
// row=h (quad*4+r). Epilogue becomes: 8 in-register relu-fma per lane,
// 2 shfl_xor (cross-quad partial sum), one coalesced 16-lane 64-B store.
// Replaces the 16-shuffle h-reduce + 4 bil shuffles + divergent writes
// (~20 serialized DS ops/tile -> 2). bil needs no shuffle: the owner lane
// (quad==0, l15=edge) computed it locally (replicated across quads).
// launch_bounds(256,2): natural VGPR ~56, no spill (R14 lesson).
// ---------------------------------------------------------------------------
__global__ __launch_bounds__(256, 2) void edge_kernel(
    const unsigned char* __restrict__ zb4, const int* __restrict__ ei,
    const float* __restrict__ s1, const float* __restrict__ s2,
    const unsigned char* __restrict__ w1T8, const unsigned char* __restrict__ w1T4,
    const float* __restrict__ b1,
    const float* __restrict__ w2, const float* __restrict__ b2,
    const float* __restrict__ bias, float* __restrict__ out,
    int nE, int nTiles)
{
    const int lane = threadIdx.x & 63;
    const int wv   = threadIdx.x >> 6;
    const int l15  = lane & 15;
    const int quad = lane >> 4;

    const int t0 = blockIdx.x * 4 + wv;
    const int nW = gridDim.x * 4;
    if (t0 >= nTiles) return;

    // weight fragments (A-operand now): lane l15 = h, quad = k-chunk.
    i32x8 W0c0, W0c1, W1c0, W1c1, W0c2, W1c2;
    {
        const unsigned char* p0 = w1T4 + (size_t)l15 * (KTOT / 2) + quad * 16;
        const unsigned char* p1 = w1T4 + (size_t)(16 + l15) * (KTOT / 2) + quad * 16;
        W0c0 = lo4(*(const int4*)(p0));
        W0c1 = lo4(*(const int4*)(p0 + 64));
        W1c0 = lo4(*(const int4*)(p1));
        W1c1 = lo4(*(const int4*)(p1 + 64));
        W0c2 = ld32(w1T8 + (size_t)l15 * KTOT + 256 + quad * 32);
        W1c2 = ld32(w1T8 + (size_t)(16 + l15) * KTOT + 256 + quad * 32);
    }
    // per-lane epilogue constants: this lane owns h rows {quad*4+r, 16+quad*4+r}
    float b1q0[4], w2q0[4], b1q1[4], w2q1[4];
#pragma unroll
    for (int r = 0; r < 4; r++) {
        b1q0[r] = b1[quad * 4 + r];       w2q0[r] = w2[quad * 4 + r];
        b1q1[r] = b1[16 + quad * 4 + r];  w2q1[r] = w2[16 + quad * 4 + r];
    }
    const float cbias = bias[0] + b2[0];

    for (int t = t0; t < nTiles; t += nW) {
        const int e = t * TPW + l15;
        int s_ = 0, d_ = 0;
        if (e < nE) { s_ = ei[e]; d_ = ei[nE + e]; }
        const float bil = s1[s_] * s2[d_];     // replicated across quads

        // fp4 row gathers (B-operand: l15 = edge col, quad = k-chunk)
        int4 zs4 = *(const int4*)(zb4 + (size_t)s_ * 64 + quad * 16);
        int4 zd4 = *(const int4*)(zb4 + (size_t)d_ * 64 + quad * 16);

        f32x4 acc0 = {0.f, 0.f, 0.f, 0.f};    // h rows 0..15
        f32x4 acc1 = {0.f, 0.f, 0.f, 0.f};    // h rows 16..31
        i32x8 zsB = lo4(zs4), zdB = lo4(zd4);
        acc0 = MFMA_F4(W0c0, zsB, acc0);
        acc1 = MFMA_F4(W1c0, zsB, acc1);
        acc0 = MFMA_F4(W0c1, zdB, acc0);
        acc1 = MFMA_F4(W1c1, zdB, acc1);
        i32x8 p8 = prod_fp4_to_fp8(zs4, zd4);
        acc0 = MFMA_F8(W0c2, p8, acc0);
        acc1 = MFMA_F8(W1c2, p8, acc1);

        // epilogue: in-register h-partial, 2 shuffles, coalesced store.
        float v = 0.f;
#pragma unroll
        for (int r = 0; r < 4; r++) {
            v += fmaxf(acc0[r] + b1q0[r], 0.f) * w2q0[r];
            v += fmaxf(acc1[r] + b1q1[r], 0.f) * w2q1[r];
        }
        v += __shfl_xor(v, 16);
        v += __shfl_xor(v, 32);
        if (quad == 0 && e < nE)
            out[e] = v + bil + cbias;          // 16 lanes, 64-B coalesced
    }
}

// ---------------------------------------------------------------------------
// Workspace: zb4 uchar[nNodes*64] | s1 f32[nNodes] | s2 f32[nNodes]
//          | wsum f32[128] | w1T8 uchar[32*384] | w1T4 uchar[32*192] (~7.2 MB)
// ---------------------------------------------------------------------------
extern "C" void kernel_launch(void* const* d_in, const int* in_sizes, int n_in,
                              void* d_out, int out_size, void* d_ws, size_t ws_size,
                              hipStream_t stream)
{
    const float* z    = (const float*)d_in[0];
    const int*   ei   = (const int*)d_in[1];
    const float* W    = (const float*)d_in[2];
    const float* bias = (const float*)d_in[3];
    const float* w1   = (const float*)d_in[4];
    const float* b1   = (const float*)d_in[5];
    const float* w2   = (const float*)d_in[6];
    const float* b2   = (const float*)d_in[7];
    float* out = (float*)d_out;

    const int nNodes = in_sizes[0] / DIM;
    const int nE = out_size;

    unsigned char* zb4 = (unsigned char*)d_ws;
    float* s1   = (float*)(zb4 + (size_t)nNodes * 64);
    float* s2   = s1 + nNodes;
    float* wsum = s2 + nNodes;
    unsigned char* w1T8 = (unsigned char*)(wsum + DIM);
    unsigned char* w1T4 = w1T8 + (size_t)HID * KTOT;

    wsum_kernel<<<32, 256, 0, stream>>>(W, wsum);

    const int nNodeBlk = (nNodes + 7) / 8;
    prep_kernel<<<nNodeBlk + 48 + 24, 256, 0, stream>>>(z, w1, wsum, zb4, w1T8,
                                                        w1T4, s1, s2,
                                                        nNodes, nNodeBlk);

    const int nTiles = (nE + TPW - 1) / TPW;
    int grid = 2048;
    if (grid * 4 > nTiles) grid = (nTiles + 3) / 4;
    edge_kernel<<<grid, 256, 0, stream>>>(zb4, ei, s1, s2, w1T8, w1T4,
                                          b1, w2, b2, bias, out, nE, nTiles);
}